// Round 2
// baseline (150.187 us; speedup 1.0000x reference)
//
#include <hip/hip_runtime.h>
#include <math.h>

#define NB_B 4
#define NB_N 8
#define NB_C 256
#define NB_K 16
#define NB_P 4096
#define NB_BN (NB_B * NB_N)

// workspace float offsets
#define WS_WSUM 0
#define WS_VSUM (NB_BN * NB_C)                    // 8192
#define WS_GT   (2 * NB_BN * NB_C)                // 16384
#define WS_DEN  (WS_GT + NB_B * NB_C)             // 17408
#define WS_NB   17440                             // normalized bank (scores)
#define WS_PN   (WS_NB + NB_BN * NB_K * NB_C)     // 148512: proto_new (map)
#define WS_VAL  (WS_PN + NB_BN * NB_K * NB_C)     // 279584

// ---------------- block reduction helpers (blockDim == 256, 4 waves) ----------------
__device__ __forceinline__ float2 blk_sum2(float a, float b, float2* sbuf) {
#pragma unroll
  for (int off = 32; off > 0; off >>= 1) {
    a += __shfl_down(a, off, 64);
    b += __shfl_down(b, off, 64);
  }
  int lane = threadIdx.x & 63, wid = threadIdx.x >> 6;
  __syncthreads();                  // protect sbuf from previous use
  if (lane == 0) sbuf[wid] = make_float2(a, b);
  __syncthreads();
  float2 r;
  r.x = sbuf[0].x + sbuf[1].x + sbuf[2].x + sbuf[3].x;
  r.y = sbuf[0].y + sbuf[1].y + sbuf[2].y + sbuf[3].y;
  return r;
}

__device__ __forceinline__ float2 blk_max2(float a, float b, float2* sbuf) {
#pragma unroll
  for (int off = 32; off > 0; off >>= 1) {
    a = fmaxf(a, __shfl_down(a, off, 64));
    b = fmaxf(b, __shfl_down(b, off, 64));
  }
  int lane = threadIdx.x & 63, wid = threadIdx.x >> 6;
  __syncthreads();
  if (lane == 0) sbuf[wid] = make_float2(a, b);
  __syncthreads();
  float2 r;
  r.x = fmaxf(fmaxf(sbuf[0].x, sbuf[1].x), fmaxf(sbuf[2].x, sbuf[3].x));
  r.y = fmaxf(fmaxf(sbuf[0].y, sbuf[1].y), fmaxf(sbuf[2].y, sbuf[3].y));
  return r;
}

// ---------------- robust decoding of the bool `valid` input ----------------
__device__ __forceinline__ int validMode(const void* vptr) {
  const unsigned int* w = (const unsigned int*)vptr;
  int mode = 0;  // 0 = int32
  for (int i = 0; i < 128; ++i) {
    unsigned int x = w[i];
    if (x == 0x3f800000u) return 2;      // float32 1.0 present -> f32
    if (x > 1u) mode = 1;                // packed bytes -> uint8
  }
  return mode;
}
__device__ __forceinline__ bool getValid(const void* vptr, int mode, int idx) {
  if (mode == 1) return ((const unsigned char*)vptr)[idx] != 0;
  if (mode == 2) return ((const float*)vptr)[idx] != 0.0f;
  return ((const int*)vptr)[idx] != 0;
}

// ---------------- kernel 1: big reductions over P ----------------
__global__ __launch_bounds__(256) void k1_reduce(
    const float* __restrict__ value, const float* __restrict__ frame,
    const float* __restrict__ mask, float* __restrict__ ws) {
  __shared__ float2 sbuf[4];
  int gid = blockIdx.x, tid = threadIdx.x;
  if (gid < NB_BN * NB_C) {
    int bn = gid >> 8;
    const float4* v4 = (const float4*)(value + (size_t)gid * NB_P);
    const float4* m4 = (const float4*)(mask + (size_t)bn * NB_P);
    float wsum = 0.f, vsum = 0.f;
#pragma unroll
    for (int i = 0; i < NB_P / 4 / 256; ++i) {
      float4 a = v4[i * 256 + tid];
      float4 m = m4[i * 256 + tid];
      wsum += a.x * m.x + a.y * m.y + a.z * m.z + a.w * m.w;
      vsum += a.x + a.y + a.z + a.w;
    }
    float2 r = blk_sum2(wsum, vsum, sbuf);
    if (tid == 0) { ws[WS_WSUM + gid] = r.x; ws[WS_VSUM + gid] = r.y; }
  } else if (gid < NB_BN * NB_C + NB_B * NB_C) {
    int idx = gid - NB_BN * NB_C;
    const float4* f4 = (const float4*)(frame + (size_t)idx * NB_P);
    float s = 0.f;
#pragma unroll
    for (int i = 0; i < 4; ++i) {
      float4 a = f4[i * 256 + tid];
      s += a.x + a.y + a.z + a.w;
    }
    float2 r = blk_sum2(s, 0.f, sbuf);
    if (tid == 0) ws[WS_GT + idx] = r.x * (1.0f / NB_P);
  } else {
    int bn = gid - NB_BN * NB_C - NB_B * NB_C;
    const float4* m4 = (const float4*)(mask + (size_t)bn * NB_P);
    float s = 0.f;
#pragma unroll
    for (int i = 0; i < 4; ++i) {
      float4 a = m4[i * 256 + tid];
      s += a.x + a.y + a.z + a.w;
    }
    float2 r = blk_sum2(s, 0.f, sbuf);
    if (tid == 0) ws[WS_DEN + bn] = r.x;
  }
}

// ---------------- kernel 2: per-(b,n) policy + bank update ----------------
__global__ __launch_bounds__(256) void k2_policy(
    const float* __restrict__ proto, const float* __restrict__ age,
    const float* __restrict__ usage, const float* __restrict__ conf,
    const void* __restrict__ valid, const float* __restrict__ W1,
    const float* __restrict__ b1, const float* __restrict__ W2,
    const float* __restrict__ b2, float* __restrict__ ws,
    float* __restrict__ out_logits) {
  __shared__ float2 sbuf[4];
  __shared__ float s_cand[NB_C];
  __shared__ float s_sim[NB_K];
  __shared__ float s_invn[NB_K];
  __shared__ float s_ctx[NB_C + NB_K + 3 * NB_K];  // 320
  __shared__ int s_dec[4];  // chosen, refine, replace_like, update

  int bn = blockIdx.x;
  int b = bn >> 3;
  int c = threadIdx.x;
  int vmode = validMode(valid);

  // candidate prototype (masked mean pool, with fallback), L2-normalized
  float denom = ws[WS_DEN + bn];
  float cand;
  if (denom <= 1e-5f) cand = ws[WS_VSUM + bn * NB_C + c] * (1.0f / NB_P);
  else                cand = ws[WS_WSUM + bn * NB_C + c] / fmaxf(denom, 1e-6f);
  float2 r0 = blk_sum2(cand * cand, 0.f, sbuf);
  cand *= 1.0f / fmaxf(sqrtf(r0.x), 1e-12f);
  s_cand[c] = cand;

  // cosine similarity against the bank
  const float* pr = proto + (size_t)bn * NB_K * NB_C;
  for (int k = 0; k < NB_K; ++k) {
    float p = pr[k * NB_C + c];
    float2 rr = blk_sum2(p * p, p * cand, sbuf);
    if (c == 0) {
      float invk = 1.0f / fmaxf(sqrtf(rr.x), 1e-12f);
      s_invn[k] = invk;
      s_sim[k] = getValid(valid, vmode, bn * NB_K + k) ? rr.y * invk : -1.0f;
    }
  }

  // global max over all age / usage (512 elements each)
  float am = fmaxf(age[c], age[c + 256]);
  float um = fmaxf(usage[c], usage[c + 256]);
  float2 mx = blk_max2(am, um, sbuf);
  float age_max = fmaxf(mx.x, 1.0f);
  float use_max = fmaxf(mx.y, 1.0f);

  // context = [g_t (256), sim (16), interleaved stats (48)]
  s_ctx[c] = ws[WS_GT + b * NB_C + c];
  if (c < NB_K) {
    int k = c;
    s_ctx[NB_C + k] = s_sim[k];
    s_ctx[NB_C + NB_K + 3 * k + 0] = age[bn * NB_K + k] / age_max;
    s_ctx[NB_C + NB_K + 3 * k + 1] = usage[bn * NB_K + k] / use_max;
    s_ctx[NB_C + NB_K + 3 * k + 2] = conf[bn * NB_K + k];
  }
  __syncthreads();

  // policy MLP: hidden unit per thread, then 4 logit reductions
  float acc = b1[c];
  for (int i = 0; i < NB_C + 4 * NB_K; ++i) acc += s_ctx[i] * W1[i * 256 + c];
  float h = 0.5f * acc *
            (1.0f + tanhf(0.7978845608028654f * (acc + 0.044715f * acc * acc * acc)));
  for (int j = 0; j < 4; ++j) {
    float2 lj = blk_sum2(h * W2[c * 4 + j], 0.f, sbuf);
    if (c == 0) out_logits[bn * 4 + j] = lj.x + b2[j];
  }

  // rule-based action + slot selection (scalar, thread 0)
  if (c == 0) {
    bool anyv = false, hasfree = false;
    for (int k = 0; k < NB_K; ++k) {
      if (getValid(valid, vmode, bn * NB_K + k)) anyv = true; else hasfree = true;
    }
    int tgt = 0; float best = s_sim[0];
    for (int k = 1; k < NB_K; ++k) if (s_sim[k] > best) { best = s_sim[k]; tgt = k; }
    if (!anyv) tgt = 0;
    float max_sim = anyv ? s_sim[tgt] : 0.0f;
    int action = 1;                       // REFINE
    if (max_sim > 0.85f) action = 0;      // KEEP
    bool low = max_sim < 0.5f;
    if (low && hasfree) action = 3;       // SPAWN
    if (low && !hasfree) action = 2;      // REPLACE
    int worst = 0; float wb = -1e30f;
    for (int k = 0; k < NB_K; ++k) {
      float sc = age[bn * NB_K + k] - usage[bn * NB_K + k] - conf[bn * NB_K + k] +
                 (getValid(valid, vmode, bn * NB_K + k) ? 0.f : 1000.f);
      if (sc > wb) { wb = sc; worst = k; }
    }
    int freeslot = 0;
    for (int k = 0; k < NB_K; ++k) {
      if (!getValid(valid, vmode, bn * NB_K + k)) { freeslot = k; break; }
    }
    int chosen = tgt;
    if (action == 3) chosen = hasfree ? freeslot : worst;
    if (action == 2) chosen = worst;
    s_dec[0] = chosen;
    s_dec[1] = (action == 1);
    s_dec[2] = (action == 2 || action == 3);
    s_dec[3] = (action != 0);
  }
  __syncthreads();

  // proto_new (unnormalized, per reference) + normalized bank -> workspace
  int chosen = s_dec[0];
  float oldp = pr[chosen * NB_C + c];
  // refine candidate row (before final _l2n)
  float t = 0.9f * oldp + 0.1f * s_cand[c];
  float2 tn = blk_sum2(t * t, 0.f, sbuf);
  float invt = 1.0f / fmaxf(sqrtf(tn.x), 1e-12f);
  // chosen-row proto_new value
  float pn_chosen = s_dec[1] ? t * invt              // refine: _l2n(EMA)
                   : (s_dec[2] ? s_cand[c]           // replace/spawn: cand (unit)
                               : oldp);              // keep: raw old
  // chosen-row normalized value (_l2n of the above)
  float nb_chosen = s_dec[1] ? t * invt
                   : (s_dec[2] ? s_cand[c]
                               : oldp * s_invn[chosen]);
  float* nbp = ws + WS_NB + (size_t)bn * NB_K * NB_C;
  float* pnp = ws + WS_PN + (size_t)bn * NB_K * NB_C;
  for (int k = 0; k < NB_K; ++k) {
    float praw = pr[k * NB_C + c];
    nbp[k * NB_C + c] = (k == chosen) ? nb_chosen : praw * s_invn[k];
    pnp[k * NB_C + c] = (k == chosen) ? pn_chosen : praw;
  }
  if (c < NB_K) {
    bool v = getValid(valid, vmode, bn * NB_K + c) || (c == chosen && s_dec[3]);
    ws[WS_VAL + bn * NB_K + c] = v ? 1.0f : 0.0f;
  }
}

// ---------------- kernel 3: prototype-conditioned readout ----------------
__global__ __launch_bounds__(256) void k3_readout(
    const float* __restrict__ value, const float* __restrict__ frame,
    const float* __restrict__ ws, const float* __restrict__ pgp,
    const float* __restrict__ fgp, float* __restrict__ out) {
  __shared__ float s_nb[NB_C][NB_K];  // normalized bank (scores)
  __shared__ float s_pn[NB_C][NB_K];  // proto_new (map)
  int blk = blockIdx.x;
  int bn = blk >> 4, tile = blk & 15;
  int b = bn >> 3;
  int tid = threadIdx.x;
  int p = tile * 256 + tid;

  const float* nbp = ws + WS_NB + (size_t)bn * NB_K * NB_C;
  const float* pnp = ws + WS_PN + (size_t)bn * NB_K * NB_C;
  for (int i = tid; i < NB_K * NB_C; i += 256) {
    int k = i >> 8, c = i & 255;
    s_nb[c][k] = nbp[i];
    s_pn[c][k] = pnp[i];
  }
  int vmask = 0;
  for (int k = 0; k < NB_K; ++k)
    if (ws[WS_VAL + bn * NB_K + k] != 0.0f) vmask |= (1 << k);
  float pg = pgp[0], fg = fgp[0];
  __syncthreads();

  const float* vp = value + (size_t)bn * NB_C * NB_P + p;
  float d[NB_K];
#pragma unroll
  for (int k = 0; k < NB_K; ++k) d[k] = 0.f;
  float sumsq = 0.f;
#pragma unroll 4
  for (int c = 0; c < NB_C; ++c) {
    float v = vp[(size_t)c * NB_P];
    sumsq += v * v;
    const float4* nb4 = (const float4*)(&s_nb[c][0]);
    float4 n0 = nb4[0], n1 = nb4[1], n2 = nb4[2], n3 = nb4[3];
    d[0] += v * n0.x;  d[1] += v * n0.y;  d[2] += v * n0.z;  d[3] += v * n0.w;
    d[4] += v * n1.x;  d[5] += v * n1.y;  d[6] += v * n1.z;  d[7] += v * n1.w;
    d[8] += v * n2.x;  d[9] += v * n2.y;  d[10] += v * n2.z; d[11] += v * n2.w;
    d[12] += v * n3.x; d[13] += v * n3.y; d[14] += v * n3.z; d[15] += v * n3.w;
  }
  float invv = 1.0f / fmaxf(sqrtf(sumsq), 1e-12f);
  float m = -1e30f;
#pragma unroll
  for (int k = 0; k < NB_K; ++k) {
    d[k] *= invv;
    if ((vmask >> k) & 1) m = fmaxf(m, d[k]);
  }
  float w[NB_K]; float ssum = 0.f;
#pragma unroll
  for (int k = 0; k < NB_K; ++k) {
    float e = ((vmask >> k) & 1) ? __expf(d[k] - m) : 0.f;
    w[k] = e; ssum += e;
  }
  float isum = vmask ? (1.0f / ssum) : 0.0f;
#pragma unroll
  for (int k = 0; k < NB_K; ++k) w[k] *= isum;

  const float* fp = frame + (size_t)b * NB_C * NB_P + p;
  float* op = out + (size_t)bn * NB_C * NB_P + p;
#pragma unroll 2
  for (int c = 0; c < NB_C; ++c) {
    float v = vp[(size_t)c * NB_P];
    float f = fp[(size_t)c * NB_P];
    const float4* pn4 = (const float4*)(&s_pn[c][0]);
    float4 n0 = pn4[0], n1 = pn4[1], n2 = pn4[2], n3 = pn4[3];
    float pm = w[0] * n0.x + w[1] * n0.y + w[2] * n0.z + w[3] * n0.w +
               w[4] * n1.x + w[5] * n1.y + w[6] * n1.z + w[7] * n1.w +
               w[8] * n2.x + w[9] * n2.y + w[10] * n2.z + w[11] * n2.w +
               w[12] * n3.x + w[13] * n3.y + w[14] * n3.z + w[15] * n3.w;
    op[(size_t)c * NB_P] = v + pg * pm + fg * f;
  }
}

extern "C" void kernel_launch(void* const* d_in, const int* in_sizes, int n_in,
                              void* d_out, int out_size, void* d_ws, size_t ws_size,
                              hipStream_t stream) {
  const float* value = (const float*)d_in[0];
  const float* frame = (const float*)d_in[1];
  const float* mask  = (const float*)d_in[2];
  const float* proto = (const float*)d_in[3];
  const float* age   = (const float*)d_in[4];
  const float* usage = (const float*)d_in[5];
  const float* conf  = (const float*)d_in[6];
  const void*  valid = (const void*)d_in[7];
  const float* W1 = (const float*)d_in[8];
  const float* b1 = (const float*)d_in[9];
  const float* W2 = (const float*)d_in[10];
  const float* b2 = (const float*)d_in[11];
  const float* pg = (const float*)d_in[12];
  const float* fg = (const float*)d_in[13];
  float* out = (float*)d_out;
  float* ws = (float*)d_ws;

  int g1 = NB_BN * NB_C + NB_B * NB_C + NB_BN;  // 9248
  hipLaunchKernelGGL(k1_reduce, dim3(g1), dim3(256), 0, stream,
                     value, frame, mask, ws);
  hipLaunchKernelGGL(k2_policy, dim3(NB_BN), dim3(256), 0, stream,
                     proto, age, usage, conf, valid, W1, b1, W2, b2, ws,
                     out + (size_t)NB_BN * NB_C * NB_P);
  hipLaunchKernelGGL(k3_readout, dim3(NB_BN * 16), dim3(256), 0, stream,
                     value, frame, ws, pg, fg, out);
}